// Round 9
// baseline (199.850 us; speedup 1.0000x reference)
//
#include <hip/hip_runtime.h>
#include <hip/hip_bf16.h>
#include <stdint.h>

#define B_ROWS 8192
#define DIM 256
#define JCHUNK 512
#define WPB 4   // waves per block
#define ROWS_PER_WAVE 32
#define ROWS_PER_BLOCK (WPB * ROWS_PER_WAVE)  // 128
#define TCOLS 32                              // j-cols per phase (one 32x32 MFMA panel)
#define NTP (JCHUNK / TCOLS)                  // 16 phases per block
#define TILE_BYTES (TCOLS * 512)              // 16 KB

typedef __bf16 bf16x8 __attribute__((ext_vector_type(8)));
typedef float f32x16 __attribute__((ext_vector_type(16)));

#if __has_builtin(__builtin_amdgcn_exp2f)
#define EXP2F(x) __builtin_amdgcn_exp2f(x)
#else
#define EXP2F(x) exp2f(x)
#endif

__device__ __forceinline__ unsigned short f2bf_rne(float f) {
    unsigned int u = __builtin_bit_cast(unsigned int, f);
    unsigned int r = (u + 0x7FFFu + ((u >> 16) & 1u)) >> 16;
    return (unsigned short)r;
}

// async global->LDS, 16B per lane; LDS dest is wave-uniform base + lane*16 (linear)
__device__ __forceinline__ void gld_lds16(const void* g, void* l) {
    __builtin_amdgcn_global_load_lds(
        (const __attribute__((address_space(1))) unsigned int*)g,
        (__attribute__((address_space(3))) unsigned int*)l, 16, 0, 0);
}

// ---------------- Kernel 1: L2-normalize rows -> bf16, zero accumulators + counter ----------------
__global__ __launch_bounds__(256) void normalize_k(const float* __restrict__ emb,
                                                   unsigned short* __restrict__ ebf,
                                                   float* __restrict__ Sall,
                                                   unsigned int* __restrict__ ctr) {
    const int idx = blockIdx.x * 256 + threadIdx.x;
    if (idx < 4096) {
        float4 z = {0.f, 0.f, 0.f, 0.f};
        reinterpret_cast<float4*>(Sall)[idx] = z;  // zeroes Sall+Spos (16384 floats)
    }
    if (idx == 0) *ctr = 0u;
    const int row = blockIdx.x * 4 + (threadIdx.x >> 6);
    const int lane = threadIdx.x & 63;  // 4 floats each covers DIM=256
    const float4 v = reinterpret_cast<const float4*>(emb + (size_t)row * DIM)[lane];
    float ss = v.x * v.x + v.y * v.y + v.z * v.z + v.w * v.w;
    #pragma unroll
    for (int off = 32; off; off >>= 1) ss += __shfl_xor(ss, off);
    const float scale = 1.0f / fmaxf(sqrtf(ss), 1e-12f);
    ushort4 o;
    o.x = f2bf_rne(v.x * scale);
    o.y = f2bf_rne(v.y * scale);
    o.z = f2bf_rne(v.z * scale);
    o.w = f2bf_rne(v.w * scale);
    reinterpret_cast<ushort4*>(ebf + (size_t)row * DIM)[lane] = o;
}

// ---------------- Kernel 2: fused sim + masked exp-sum (32x32x16 MFMA shape) ----------------
// Shape change rationale (R0-R7 evidence): the 64-row/wave 16x16 shape is register-
// saturated at 2 waves/SIMD (every variant that added liveness spilled; removing
// barriers was neutral) -> latency-bound at ~25% MfmaUtil. This kernel:
//  - 32 rows/wave via ONE mfma_f32_32x32x16_bf16 chain: afrag 64 VGPR (was 128),
//    acc 16, sums 32, packed labels 8 -> ~140 total, fits __launch_bounds__(256,3)
//    -> 3 waves/SIMD (1.5x occupancy).
//  - 2x fewer MFMA instructions at 1.25x pipe rate (8cyc/32K-FLOP, m119).
//  - Cooperative global_load_lds staging (0 staging registers), double-buffered
//    16KB tile, plain __syncthreads (loads span the whole phase before the drain).
//  - XOR bank-swizzle via pre-swizzled GLOBAL source, linear LDS dest (proven R6/R7).
//  - Fragment layouts: A/B mirror the proven 16x16 mapping with &31/>>5;
//    C/D col=lane&31, row=(reg&3)+8*(reg>>2)+4*(lane>>5) (m74/m101-verified).
//  - finalize fused into the last sim_k block (device-scope counter), one launch saved.
__global__ __launch_bounds__(256, 3) void sim_k(const unsigned short* __restrict__ ebf,
                                                const int* __restrict__ labels,
                                                float* __restrict__ Sall,
                                                float* __restrict__ Spos,
                                                unsigned int* __restrict__ ctr,
                                                float* __restrict__ out) {
    // exp((dot-1)/T) = exp2((dot-1) * INV_T*log2e)
    constexpr float K2 = 14.285714285714286f * 1.4426950408889634f;  // 20.60993
    __shared__ __align__(16) unsigned char bufs[2][TILE_BYTES];      // 32 KB
    __shared__ int lds_lab[JCHUNK];
    __shared__ int lastblk;
    __shared__ float fsum[WPB];
    __shared__ int fcnt[WPB];

    const int tid  = threadIdx.x;
    const int wave = tid >> 6;
    const int lane = tid & 63;
    const int lo   = lane & 31;
    const int hi   = lane >> 5;

    const int rowblk = blockIdx.x >> 4;            // 0..63
    const int jblk   = blockIdx.x & 15;            // 0..15
    const int i_base = rowblk * ROWS_PER_BLOCK + wave * ROWS_PER_WAVE;
    const int j0     = jblk * JCHUNK;

    // ---- Preload A-fragments: lane holds A[row=i_base+lo][k = ks*16 + hi*8 + 0..7]
    bf16x8 afrag[16];
    {
        const char* aRow = reinterpret_cast<const char*>(ebf) + (size_t)(i_base + lo) * 512 + hi * 16;
        #pragma unroll
        for (int ks = 0; ks < 16; ++ks)
            afrag[ks] = *reinterpret_cast<const bf16x8*>(aRow + ks * 32);
    }
    // ---- Row labels for this lane's 16 C/D slots, packed 2x16b (rows < 1000 fit)
    // row_local(reg) = (reg&3) + 8*(reg>>2) + 4*hi
    unsigned lab2[8];
    #pragma unroll
    for (int jj = 0; jj < 8; ++jj) {
        const int r0 = ((2 * jj) & 3) + 8 * ((2 * jj) >> 2) + 4 * hi;
        const int r1 = ((2 * jj + 1) & 3) + 8 * ((2 * jj + 1) >> 2) + 4 * hi;
        lab2[jj] = (unsigned)(labels[i_base + r0] & 0xffff) |
                   ((unsigned)labels[i_base + r1] << 16);
    }

    // ---- Per-lane pre-swizzled global source offsets for staging ----
    // Wave w stages LDS bytes [w*4096 + i*1024): rows r = 8w + 2i + hi of the
    // 32-row tile, lane slot s = lo. XOR layout (slot s of row r holds global
    // chunk s^r) with LINEAR LDS dest -> lane fetches global chunk (s^r)&31.
    int voff[4];
    #pragma unroll
    for (int i = 0; i < 4; ++i) {
        const int r = 8 * wave + 2 * i + hi;
        voff[i] = r * 512 + ((lo ^ r) & 31) * 16;
    }
    const int ldst0 = wave * 4096;

    const char* gBase = reinterpret_cast<const char*>(ebf) + (size_t)j0 * 512;

    // ---- Prologue: labels -> LDS; stage tile 0 into bufs[0] ----
    lds_lab[tid] = labels[j0 + tid];
    lds_lab[256 + tid] = labels[j0 + 256 + tid];
    #pragma unroll
    for (int i = 0; i < 4; ++i)
        gld_lds16(gBase + voff[i], bufs[0] + ldst0 + i * 1024);
    __syncthreads();

    float s_all[16] = {};
    float s_pos[16] = {};

    for (int jt = 0; jt < NTP; ++jt) {
        unsigned char* bufR = bufs[jt & 1];
        unsigned char* bufW = bufs[(jt + 1) & 1];

        // issue next tile's staging; lands during this phase's compute,
        // drained by the phase-ending __syncthreads (m97 pattern)
        if ((jt + 1) < NTP) {
            const char* gT = gBase + (size_t)(jt + 1) * TILE_BYTES;
            #pragma unroll
            for (int i = 0; i < 4; ++i)
                gld_lds16(gT + voff[i], bufW + ldst0 + i * 1024);
        }

        // ---- 16 k-steps, single 32x32x16 acc chain ----
        f32x16 acc = {};
        __builtin_amdgcn_s_setprio(1);
        #pragma unroll
        for (int ks = 0; ks < 16; ++ks) {
            const int c = ks * 2 + hi;
            const bf16x8 bfrag = *reinterpret_cast<const bf16x8*>(
                &bufR[lo * 512 + ((c ^ lo) & 31) * 16]);
            acc = __builtin_amdgcn_mfma_f32_32x32x16_bf16(afrag[ks], bfrag, acc, 0, 0, 0);
        }
        __builtin_amdgcn_s_setprio(0);

        // ---- Epilogue: D col = lo, row = (reg&3)+8*(reg>>2)+4*hi ----
        const int lj = lds_lab[jt * TCOLS + lo];
        const int strip = j0 + jt * TCOLS;
        const int jcol = strip + lo;
        const bool diag_possible = (strip == i_base);  // both 32-aligned strips
        if (!diag_possible) {
            #pragma unroll
            for (int reg = 0; reg < 16; ++reg) {
                const float ex = EXP2F(fmaf(acc[reg], K2, -K2));
                const int li = (int)((lab2[reg >> 1] >> ((reg & 1) * 16)) & 0xffff);
                s_all[reg] += ex;
                s_pos[reg] += (lj == li) ? ex : 0.0f;
            }
        } else {
            #pragma unroll
            for (int reg = 0; reg < 16; ++reg) {
                const int rl = (reg & 3) + 8 * (reg >> 2) + 4 * hi;
                const int irow = i_base + rl;
                const float ex = EXP2F(fmaf(acc[reg], K2, -K2));
                const int li = (int)((lab2[reg >> 1] >> ((reg & 1) * 16)) & 0xffff);
                const bool valid = (jcol != irow);
                const bool pos = valid && (lj == li);
                s_all[reg] += valid ? ex : 0.0f;
                s_pos[reg] += pos ? ex : 0.0f;
            }
        }

        __syncthreads();
    }

    // ---- Reduce over the 32 column-lanes (per half), one atomic per row ----
    #pragma unroll
    for (int reg = 0; reg < 16; ++reg) {
        float a = s_all[reg];
        float pp = s_pos[reg];
        #pragma unroll
        for (int off = 1; off < 32; off <<= 1) {
            a += __shfl_xor(a, off);
            pp += __shfl_xor(pp, off);
        }
        if (lo == 0) {
            const int irow = i_base + (reg & 3) + 8 * (reg >> 2) + 4 * hi;
            atomicAdd(&Sall[irow], a);
            atomicAdd(&Spos[irow], pp);
        }
    }

    // ---- Fused finalize: last block computes the mean loss ----
    __threadfence();
    if (tid == 0) {
        const unsigned prev = atomicAdd(ctr, 1u);
        lastblk = (prev == (unsigned)(gridDim.x - 1)) ? 1 : 0;
    }
    __syncthreads();
    if (lastblk) {
        __threadfence();  // acquire side
        float sum = 0.0f;
        int cnt = 0;
        for (int i = tid; i < B_ROWS; i += 256) {
            const float sp = __hip_atomic_load(&Spos[i], __ATOMIC_RELAXED, __HIP_MEMORY_SCOPE_AGENT);
            const float sa = __hip_atomic_load(&Sall[i], __ATOMIC_RELAXED, __HIP_MEMORY_SCOPE_AGENT);
            if (sp > 0.0f) {
                sum += __logf(__fdividef(sa, sp));
                ++cnt;
            }
        }
        #pragma unroll
        for (int off = 32; off; off >>= 1) {
            sum += __shfl_xor(sum, off);
            cnt += __shfl_xor(cnt, off);
        }
        if (lane == 0) { fsum[wave] = sum; fcnt[wave] = cnt; }
        __syncthreads();
        if (tid == 0) {
            float s = 0.0f;
            int c = 0;
            #pragma unroll
            for (int w = 0; w < WPB; ++w) { s += fsum[w]; c += fcnt[w]; }
            out[0] = (c > 0) ? s / (float)c : 0.0f;
        }
    }
}

extern "C" void kernel_launch(void* const* d_in, const int* in_sizes, int n_in,
                              void* d_out, int out_size, void* d_ws, size_t ws_size,
                              hipStream_t stream) {
    const float* emb   = (const float*)d_in[0];
    const int* labels  = (const int*)d_in[1];
    float* out         = (float*)d_out;

    unsigned short* ebf = (unsigned short*)d_ws;                       // 4 MB bf16 normalized
    float* Sall = (float*)((char*)d_ws + (size_t)B_ROWS * DIM * 2);    // 32 KB
    float* Spos = Sall + B_ROWS;                                       // 32 KB
    unsigned int* ctr = (unsigned int*)(Spos + B_ROWS);                // 4 B

    normalize_k<<<B_ROWS / 4, 256, 0, stream>>>(emb, ebf, Sall, ctr);

    dim3 grid((B_ROWS / ROWS_PER_BLOCK) * (B_ROWS / JCHUNK));          // 64*16 = 1024
    sim_k<<<grid, 256, 0, stream>>>(ebf, labels, Sall, Spos, ctr, out);
}

// Round 10
// 111.512 us; speedup vs baseline: 1.7922x; 1.7922x over previous
//
#include <hip/hip_runtime.h>
#include <hip/hip_bf16.h>
#include <stdint.h>

#define B_ROWS 8192
#define DIM 256
#define JCHUNK 512
#define WPB 4   // waves per block
#define ROWS_PER_WAVE 64
#define ROWS_PER_BLOCK (WPB * ROWS_PER_WAVE)  // 256
#define NT (JCHUNK / 16)                      // 32 j-tiles per block
#define NTILES 4                              // A row-tiles per wave

typedef __bf16 bf16x8 __attribute__((ext_vector_type(8)));
typedef float f32x4 __attribute__((ext_vector_type(4)));

#if __has_builtin(__builtin_amdgcn_exp2f)
#define EXP2F(x) __builtin_amdgcn_exp2f(x)
#else
#define EXP2F(x) exp2f(x)
#endif

__device__ __forceinline__ unsigned short f2bf_rne(float f) {
    unsigned int u = __builtin_bit_cast(unsigned int, f);
    unsigned int r = (u + 0x7FFFu + ((u >> 16) & 1u)) >> 16;
    return (unsigned short)r;
}

// async global->LDS, 16B per lane; LDS dest is wave-uniform base + lane*16 (linear)
__device__ __forceinline__ void gld_lds16(const void* g, void* l) {
    __builtin_amdgcn_global_load_lds(
        (const __attribute__((address_space(1))) unsigned int*)g,
        (__attribute__((address_space(3))) unsigned int*)l, 16, 0, 0);
}

// ---------------- Kernel 1: L2-normalize rows -> bf16, plus zero accumulators ----------------
__global__ __launch_bounds__(256) void normalize_k(const float* __restrict__ emb,
                                                   unsigned short* __restrict__ ebf,
                                                   float* __restrict__ Sall) {  // 2*8192 floats
    const int idx = blockIdx.x * 256 + threadIdx.x;
    if (idx < 4096) {
        float4 z = {0.f, 0.f, 0.f, 0.f};
        reinterpret_cast<float4*>(Sall)[idx] = z;
    }
    const int row = blockIdx.x * 4 + (threadIdx.x >> 6);
    const int lane = threadIdx.x & 63;  // 4 floats each covers DIM=256
    const float4 v = reinterpret_cast<const float4*>(emb + (size_t)row * DIM)[lane];
    float ss = v.x * v.x + v.y * v.y + v.z * v.z + v.w * v.w;
    #pragma unroll
    for (int off = 32; off; off >>= 1) ss += __shfl_xor(ss, off);
    const float scale = 1.0f / fmaxf(sqrtf(ss), 1e-12f);
    ushort4 o;
    o.x = f2bf_rne(v.x * scale);
    o.y = f2bf_rne(v.y * scale);
    o.z = f2bf_rne(v.z * scale);
    o.w = f2bf_rne(v.w * scale);
    reinterpret_cast<ushort4*>(ebf + (size_t)row * DIM)[lane] = o;
}

// ---------------- Kernel 2: fused sim + masked exp-sum, PIPELINED EPILOGUE ----------------
// R9 top-down pipe accounting of the 51us baseline: MFMA 16.6us + exp(trans) 13.7us
// + LDS 10.2us + VALU 3.4us on DIFFERENT pipes, running serially (sum ~44us ~= wall)
// because each phase is ds_read->MFMA->(acc wait)->exp-epilogue in-order, barrier-
// locked. Fix: accumulator DOUBLE-BUFFER (accA/accB, +16 AGPR only -- every spilled
// round added VGPR-heavy liveness instead) with the epilogue of phase p deferred and
// emitted AFTER the MFMA issue of phase p+1: exp/VALU of p overlaps the MFMA drain
// of p+1 within the wave. Staging: cooperative global_load_lds (0 staging regs,
// R6-proven), double LDS buffer, plain __syncthreads (m97 pattern; loads span the
// whole phase). XOR swizzle via pre-swizzled GLOBAL source, linear LDS dest
// (R6-proven absmax=0); ds_read side is the measured-0-conflict layout.
__global__ __launch_bounds__(256, 2) void sim_k(const unsigned short* __restrict__ ebf,
                                                const int* __restrict__ labels,
                                                float* __restrict__ Sall,
                                                float* __restrict__ Spos) {
    // exp((dot-1)/T) = exp2((dot-1) * INV_T*log2e)
    constexpr float K2 = 14.285714285714286f * 1.4426950408889634f;  // 20.60993
    __shared__ __align__(16) unsigned char bufs[2][8192];            // 16 KB
    __shared__ int lds_lab[JCHUNK];

    const int tid  = threadIdx.x;
    const int wave = tid >> 6;
    const int lane = tid & 63;
    const int col  = lane & 15;
    const int quad = lane >> 4;
    const int lo   = lane & 31;
    const int hi   = lane >> 5;

    const int rowblk = blockIdx.x >> 4;            // 0..31
    const int jblk   = blockIdx.x & 15;            // 0..15
    const int i_base = rowblk * ROWS_PER_BLOCK + wave * ROWS_PER_WAVE;
    const int j0     = jblk * JCHUNK;

    // ---- Preload A-fragments (4 tiles x 8 K-steps) + row labels ----
    // lane L holds A[row = L&15][k = kk*32 + (L>>4)*8 + 0..7]
    bf16x8 afrag[NTILES][8];
    int li[NTILES][4];
    #pragma unroll
    for (int t = 0; t < NTILES; ++t) {
        const int arow = i_base + t * 16 + col;
        const uint4* ap = reinterpret_cast<const uint4*>(ebf) + (size_t)arow * 32 + quad;
        #pragma unroll
        for (int kk = 0; kk < 8; ++kk)
            afrag[t][kk] = __builtin_bit_cast(bf16x8, ap[kk * 4]);
        #pragma unroll
        for (int r = 0; r < 4; ++r)
            li[t][r] = labels[i_base + t * 16 + quad * 4 + r];
    }

    // ---- Per-lane pre-swizzled global source offsets (R6-proven) ----
    // Wave w stages LDS bytes [w*2048 + i*1024), i=0,1: rows r = 4w + 2i + hi of
    // the 16-row tile, lane slot s = lo. XOR layout (slot s of row r holds global
    // chunk s^r) with LINEAR LDS dest -> lane fetches global chunk (s^r)&31 of row r.
    int voff[2];
    #pragma unroll
    for (int i = 0; i < 2; ++i) {
        const int r = 4 * wave + 2 * i + hi;
        voff[i] = r * 512 + ((lo ^ r) & 31) * 16;
    }
    const int ldst0 = wave * 2048;

    const char* gBase = reinterpret_cast<const char*>(ebf) + (size_t)j0 * 512;

    // ---- Prologue: labels -> LDS; stage tile 0 into bufs[0] ----
    lds_lab[tid] = labels[j0 + tid];
    lds_lab[256 + tid] = labels[j0 + 256 + tid];
    gld_lds16(gBase + voff[0], bufs[0] + ldst0);
    gld_lds16(gBase + voff[1], bufs[0] + ldst0 + 1024);
    __syncthreads();

    float s_all[NTILES][4] = {};
    float s_pos[NTILES][4] = {};
    f32x4 accA[NTILES], accB[NTILES];

    // MFMA section: 8 ds_read + 32 MFMA into acc (4 independent chains)
    auto do_mfma = [&](f32x4* acc, const unsigned char* bufR) {
        #pragma unroll
        for (int t = 0; t < NTILES; ++t) acc[t] = (f32x4){0.f, 0.f, 0.f, 0.f};
        __builtin_amdgcn_s_setprio(1);
        #pragma unroll
        for (int kk = 0; kk < 8; ++kk) {
            const int c = kk * 4 + quad;
            const bf16x8 bfrag = *reinterpret_cast<const bf16x8*>(
                &bufR[col * 512 + ((c ^ col) & 31) * 16]);
            #pragma unroll
            for (int t = 0; t < NTILES; ++t)
                acc[t] = __builtin_amdgcn_mfma_f32_16x16x32_bf16(afrag[t][kk], bfrag, acc[t], 0, 0, 0);
        }
        __builtin_amdgcn_s_setprio(0);
    };

    // Deferred epilogue for phase jt (acc computed one phase earlier; ready)
    auto do_epi = [&](const f32x4* acc, int jt) {
        const int lj = lds_lab[jt * 16 + col];
        const int jcol = j0 + jt * 16 + col;
        const int jt16 = j0 + jt * 16;
        const bool diag_possible = (jt16 < i_base + ROWS_PER_WAVE) && (i_base < jt16 + 16);
        if (!diag_possible) {
            #pragma unroll
            for (int t = 0; t < NTILES; ++t) {
                #pragma unroll
                for (int r = 0; r < 4; ++r) {
                    const float ex = EXP2F(fmaf(acc[t][r], K2, -K2));
                    s_all[t][r] += ex;
                    s_pos[t][r] += (lj == li[t][r]) ? ex : 0.0f;
                }
            }
        } else {
            #pragma unroll
            for (int t = 0; t < NTILES; ++t) {
                #pragma unroll
                for (int r = 0; r < 4; ++r) {
                    const int irow = i_base + t * 16 + quad * 4 + r;
                    const float ex = EXP2F(fmaf(acc[t][r], K2, -K2));
                    const bool valid = (jcol != irow);
                    const bool pos = valid && (lj == li[t][r]);
                    s_all[t][r] += valid ? ex : 0.0f;
                    s_pos[t][r] += pos ? ex : 0.0f;
                }
            }
        }
    };

    #pragma unroll 1
    for (int m = 0; m < NT / 2; ++m) {
        const int jt0 = 2 * m, jt1 = 2 * m + 1;

        // ---- phase jt0: read bufs[0], stage jt0+1 into bufs[1] ----
        {
            const char* gT = gBase + (size_t)(jt0 + 1) * 8192;   // jt0+1 <= 31 always
            gld_lds16(gT + voff[0], bufs[1] + ldst0);
            gld_lds16(gT + voff[1], bufs[1] + ldst0 + 1024);
        }
        do_mfma(accA, bufs[0]);
        if (m > 0) do_epi(accB, jt0 - 1);   // overlap: exp(jt0-1) under MFMA(jt0) drain
        __syncthreads();

        // ---- phase jt1: read bufs[1], stage jt1+1 into bufs[0] ----
        if (jt1 + 1 < NT) {
            const char* gT = gBase + (size_t)(jt1 + 1) * 8192;
            gld_lds16(gT + voff[0], bufs[0] + ldst0);
            gld_lds16(gT + voff[1], bufs[0] + ldst0 + 1024);
        }
        do_mfma(accB, bufs[1]);
        do_epi(accA, jt0);                  // overlap: exp(jt0) under MFMA(jt1) drain
        __syncthreads();
    }
    do_epi(accB, NT - 1);                   // tail epilogue

    // Reduce over the 16 column-lanes within each quad, then one atomic per row.
    #pragma unroll
    for (int t = 0; t < NTILES; ++t) {
        #pragma unroll
        for (int r = 0; r < 4; ++r) {
            float a = s_all[t][r];
            float pp = s_pos[t][r];
            #pragma unroll
            for (int off = 1; off < 16; off <<= 1) {
                a += __shfl_xor(a, off);
                pp += __shfl_xor(pp, off);
            }
            if (col == 0) {
                const int irow = i_base + t * 16 + quad * 4 + r;
                atomicAdd(&Sall[irow], a);
                atomicAdd(&Spos[irow], pp);
            }
        }
    }
}

// ---------------- Kernel 3: per-row loss + mean ----------------
__global__ __launch_bounds__(1024) void finalize_k(const float* __restrict__ Sall,
                                                   const float* __restrict__ Spos,
                                                   float* __restrict__ out) {
    const int tid = threadIdx.x;
    float sum = 0.0f;
    int cnt = 0;
    #pragma unroll
    for (int k = 0; k < B_ROWS / 1024; ++k) {
        const int i = k * 1024 + tid;
        const float sp = Spos[i];
        const float sa = Sall[i];
        if (sp > 0.0f) {
            sum += __logf(__fdividef(sa, sp));  // log(sa)-log(sp); fixed max M cancels
            ++cnt;
        }
    }
    #pragma unroll
    for (int off = 32; off; off >>= 1) {
        sum += __shfl_xor(sum, off);
        cnt += __shfl_xor(cnt, off);
    }
    __shared__ float ssum[16];
    __shared__ int scnt[16];
    const int wave = tid >> 6, lane = tid & 63;
    if (lane == 0) { ssum[wave] = sum; scnt[wave] = cnt; }
    __syncthreads();
    if (tid == 0) {
        float s = 0.0f;
        int c = 0;
        #pragma unroll
        for (int w = 0; w < 16; ++w) { s += ssum[w]; c += scnt[w]; }
        out[0] = (c > 0) ? s / (float)c : 0.0f;
    }
}

extern "C" void kernel_launch(void* const* d_in, const int* in_sizes, int n_in,
                              void* d_out, int out_size, void* d_ws, size_t ws_size,
                              hipStream_t stream) {
    const float* emb   = (const float*)d_in[0];
    const int* labels  = (const int*)d_in[1];
    float* out         = (float*)d_out;

    unsigned short* ebf = (unsigned short*)d_ws;                       // 4 MB bf16 normalized
    float* Sall = (float*)((char*)d_ws + (size_t)B_ROWS * DIM * 2);    // 32 KB
    float* Spos = Sall + B_ROWS;                                       // 32 KB

    normalize_k<<<B_ROWS / 4, 256, 0, stream>>>(emb, ebf, Sall);

    dim3 grid((B_ROWS / ROWS_PER_BLOCK) * (B_ROWS / JCHUNK));          // 32*16 = 512
    sim_k<<<grid, 256, 0, stream>>>(ebf, labels, Sall, Spos);

    finalize_k<<<1, 1024, 0, stream>>>(Sall, Spos, out);
}